// Round 4
// baseline (182.980 us; speedup 1.0000x reference)
//
#include <hip/hip_runtime.h>
#include <cstddef>

#define CC 256
#define HH 128
#define WW 128
#define HW (HH*WW)          // 16384

typedef __attribute__((ext_vector_type(8))) short short8v;   // 8 bf16
typedef __attribute__((ext_vector_type(4))) float float4v;   // MFMA acc

__device__ __forceinline__ short f2bf(float x) {
    unsigned u = __float_as_uint(x);
    u += 0x7FFFu + ((u >> 16) & 1u);      // RNE to bf16
    return (short)(u >> 16);
}
__device__ __forceinline__ float4 add4(float4 a, float4 b) {
    float4 r; r.x=a.x+b.x; r.y=a.y+b.y; r.z=a.z+b.z; r.w=a.w+b.w; return r;
}
__device__ __forceinline__ float4 scale4(float4 a, float s) {
    float4 r; r.x=a.x*s; r.y=a.y*s; r.z=a.z*s; r.w=a.w*s; return r;
}
__device__ __forceinline__ float4 shflx4(float4 v, int m) {
    float4 r;
    r.x = __shfl_xor(v.x, m); r.y = __shfl_xor(v.y, m);
    r.z = __shfl_xor(v.z, m); r.w = __shfl_xor(v.w, m);
    return r;
}
__device__ __forceinline__ float hsum4(float4 v) { return v.x+v.y+v.z+v.w; }

// ============ Kernel 1: fused pooling + both energies (MFMA bf16) ============
// grid 2048: b = bid&7, c = bid>>3. block 512 (8 waves).
// All global loads issued early into registers; 4 barriers per block.
__global__ __launch_bounds__(512, 4) void fused_pool_energy(
    const float* __restrict__ t1, const float* __restrict__ t2,
    float* __restrict__ valH, float* __restrict__ valW,
    float* __restrict__ PH, float* __restrict__ PW)
{
    __shared__ __align__(16) short t2lds[64*128];   // [h_local][w]  swz (h&7)<<3   16KB
    __shared__ __align__(16) short t2T  [128*64];   // [w][h_local]  swz ((w>>2)&7)<<3  16KB
    __shared__ __align__(16) short kH   [16*128];   // [k][w]        swz (k&7)<<3    4KB
    __shared__ __align__(16) short kWT  [16*128];   // [k][h global] swz (k&7)<<3    4KB

    const int bid = blockIdx.x;
    const int b   = bid & 7;
    const int c   = bid >> 3;
    const int tid = threadIdx.x;
    const int l   = tid & 63;
    const int wv  = tid >> 6;          // wave 0..7
    const int q   = tid & 31;          // float4 column 0..31
    const int g   = tid >> 5;          // row group 0..15
    const int bc  = b*CC + c;
    const size_t cbase = (size_t)bc * HW;
    const float4* t1c = (const float4*)(t1 + cbase);
    const float4* t2c = (const float4*)(t2 + cbase);

    // ---- issue t1 (8 rows x 1 f4-col) and t2 half0 (4 rows) loads ----
    float4 aR[8];
    #pragma unroll
    for (int r = 0; r < 8; ++r) aR[r] = t1c[g*256 + r*32 + q];
    float4 cR[4];
    #pragma unroll
    for (int r = 0; r < 4; ++r) cR[r] = t2c[g*128 + r*32 + q];

    // ---- Phase A: keys from t1 ----
    {
        float4 s = add4(add4(add4(aR[0],aR[1]), add4(aR[2],aR[3])),
                        add4(add4(aR[4],aR[5]), add4(aR[6],aR[7])));
        float4 m4 = scale4(s, 0.125f);
        short4 p; p.x=f2bf(m4.x); p.y=f2bf(m4.y); p.z=f2bf(m4.z); p.w=f2bf(m4.w);
        *(short4*)&kH[g*128 + ((q*4) ^ ((g&7)<<3))] = p;
        const int kw = q >> 1;
        const int sw = (kw & 7) << 3;
        #pragma unroll
        for (int r = 0; r < 8; ++r) {
            float rs = hsum4(aR[r]);
            rs += __shfl_xor(rs, 1);
            if ((l & 1) == 0)
                kWT[kw*128 + ((g*8+r) ^ sw)] = f2bf(rs * 0.125f);
        }
    }
    __syncthreads();

    float4v accH = {0.f,0.f,0.f,0.f};
    float4v accW = {0.f,0.f,0.f,0.f};
    float4 dR[4];

    #pragma unroll
    for (int half = 0; half < 2; ++half) {
        // source registers for this half
        float4 x0, x1, x2, x3;
        if (half == 0) { x0=cR[0]; x1=cR[1]; x2=cR[2]; x3=cR[3]; }
        else           { x0=dR[0]; x1=dR[1]; x2=dR[2]; x3=dR[3]; }

        if (half == 0) {
            // issue half1 loads now; they fly during half0 staging+MFMA
            #pragma unroll
            for (int r = 0; r < 4; ++r) dR[r] = t2c[2048 + g*128 + r*32 + q];
        }

        // ---- pool H (8 rows via lane^32 pairing) -> valH ----
        {
            float4 sB = add4(add4(x0,x1), add4(x2,x3));
            float4 f8 = add4(sB, shflx4(sB, 32));
            if (l < 32) {
                const int k = half*8 + wv;
                *(float4*)&valH[((size_t)bc*16 + k)*128 + q*4] = scale4(f8, 0.125f);
            }
        }
        // ---- pool W -> valW [h][k] (scalar stores, even lanes) ----
        {
            const int kw = q >> 1;
            float r0 = hsum4(x0), r1 = hsum4(x1), r2 = hsum4(x2), r3 = hsum4(x3);
            r0 += __shfl_xor(r0, 1); r1 += __shfl_xor(r1, 1);
            r2 += __shfl_xor(r2, 1); r3 += __shfl_xor(r3, 1);
            if ((l & 1) == 0) {
                const size_t vb = (size_t)bc*2048 + (size_t)(half*64 + g*4)*16 + kw;
                valW[vb +  0] = r0 * 0.125f;
                valW[vb + 16] = r1 * 0.125f;
                valW[vb + 32] = r2 * 0.125f;
                valW[vb + 48] = r3 * 0.125f;
            }
        }
        // ---- stage LDS: row-major + transposed (bf16) ----
        short4 s0, s1, s2, s3;
        s0.x=f2bf(x0.x); s0.y=f2bf(x0.y); s0.z=f2bf(x0.z); s0.w=f2bf(x0.w);
        s1.x=f2bf(x1.x); s1.y=f2bf(x1.y); s1.z=f2bf(x1.z); s1.w=f2bf(x1.w);
        s2.x=f2bf(x2.x); s2.y=f2bf(x2.y); s2.z=f2bf(x2.z); s2.w=f2bf(x2.w);
        s3.x=f2bf(x3.x); s3.y=f2bf(x3.y); s3.z=f2bf(x3.z); s3.w=f2bf(x3.w);
        {
            const int hl0 = g*4;
            *(short4*)&t2lds[(hl0+0)*128 + ((q*4) ^ (((hl0+0)&7)<<3))] = s0;
            *(short4*)&t2lds[(hl0+1)*128 + ((q*4) ^ (((hl0+1)&7)<<3))] = s1;
            *(short4*)&t2lds[(hl0+2)*128 + ((q*4) ^ (((hl0+2)&7)<<3))] = s2;
            *(short4*)&t2lds[(hl0+3)*128 + ((q*4) ^ (((hl0+3)&7)<<3))] = s3;
            // transpose 4x4 -> t2T; swz = ((w>>2)&7)<<3 = (q&7)<<3 for all 4 cols
            const int swt = (q & 7) << 3;
            const int hb  = hl0 ^ swt;
            short4 p;
            p.x=s0.x; p.y=s1.x; p.z=s2.x; p.w=s3.x;
            *(short4*)&t2T[(q*4+0)*64 + hb] = p;
            p.x=s0.y; p.y=s1.y; p.z=s2.y; p.w=s3.y;
            *(short4*)&t2T[(q*4+1)*64 + hb] = p;
            p.x=s0.z; p.y=s1.z; p.z=s2.z; p.w=s3.z;
            *(short4*)&t2T[(q*4+2)*64 + hb] = p;
            p.x=s0.w; p.y=s1.w; p.z=s2.w; p.w=s3.w;
            *(short4*)&t2T[(q*4+3)*64 + hb] = p;
        }
        __syncthreads();

        // ---- MFMA H branch: waves (half*4 .. half*4+3) own the h-tiles here ----
        if ((wv >> 2) == half) {
            const int hl = (wv & 3)*16 + (l & 15);
            const int kb = l & 15;
            #pragma unroll
            for (int ws2 = 0; ws2 < 4; ++ws2) {
                const int wb = ws2*32 + (l>>4)*8;
                short8v A = *(const short8v*)&t2lds[hl*128 + (wb ^ ((hl&7)<<3))];
                short8v B = *(const short8v*)&kH  [kb*128 + (wb ^ ((kb&7)<<3))];
                accH = __builtin_amdgcn_mfma_f32_16x16x32_bf16(A, B, accH, 0, 0, 0);
            }
        }
        // ---- MFMA W branch: all waves; wave wv owns w-tile wv ----
        {
            const int kb = l & 15;
            const int w  = wv*16 + (l & 15);
            const int swt = ((w >> 2) & 7) << 3;
            #pragma unroll
            for (int hs = 0; hs < 2; ++hs) {
                const int hloc = hs*32 + (l>>4)*8;
                const int hg   = half*64 + hloc;
                short8v A = *(const short8v*)&kWT[kb*128 + (hg ^ ((kb&7)<<3))];
                short8v B = *(const short8v*)&t2T[w*64   + (hloc ^ swt)];
                accW = __builtin_amdgcn_mfma_f32_16x16x32_bf16(A, B, accW, 0, 0, 0);
            }
        }
        __syncthreads();
    }

    // ---------- write partials ----------
    {
        const size_t pb = (size_t)bc * 2048;
        #pragma unroll
        for (int r = 0; r < 4; ++r) {
            const int h = wv*16 + (l>>4)*4 + r;
            PH[pb + h*16 + (l&15)] = accH[r];
            const int k = (l>>4)*4 + r;
            PW[pb + k*128 + wv*16 + (l&15)] = accW[r];
        }
    }
}

// ============ Kernel 2: reduce partials (256 chunks) -> energy[8][4096] ============
// grid 512, block 256: block owns 64 outputs; 4-way split-K + per-block minmax.
__global__ __launch_bounds__(256) void energy_reduce(
    const float* __restrict__ PH, const float* __restrict__ PW,
    float* __restrict__ energy, float* __restrict__ bmin, float* __restrict__ bmax)
{
    const int bidx = blockIdx.x;           // 0..511
    const int tid  = threadIdx.x;
    const int ol   = tid & 63, qd = tid >> 6;
    const int o    = bidx*64 + ol;         // 0..32767
    __shared__ float red[4][64];

    const int isW = o >> 14;               // 0: PH region, 1: PW region
    const int oo  = o & 16383;
    const int b   = oo >> 11, i = oo & 2047;
    const float* P = (isW ? PW : PH) + (size_t)b*256*2048 + i;
    float s = 0.f;
    #pragma unroll 8
    for (int j = 0; j < 64; ++j) s += P[(size_t)(qd*64 + j)*2048];
    red[qd][ol] = s;
    __syncthreads();

    if (tid < 64) {
        float v = red[0][tid] + red[1][tid] + red[2][tid] + red[3][tid];
        const int o2 = bidx*64 + tid;
        const int oo2 = o2 & 16383;
        const int b2 = oo2 >> 11, i2 = oo2 & 2047;
        const size_t dst = (o2 >> 14)
            ? ((size_t)b2*4096 + 2048 + (size_t)(i2 & 127)*16 + (i2 >> 7))
            : ((size_t)b2*4096 + i2);
        energy[dst] = v;
        float mn = v, mx = v;
        #pragma unroll
        for (int sft = 32; sft > 0; sft >>= 1) {
            mn = fminf(mn, __shfl_xor(mn, sft));
            mx = fmaxf(mx, __shfl_xor(mx, sft));
        }
        if (tid == 0) { bmin[bidx] = mn; bmax[bidx] = mx; }
    }
}

// ============ Kernel 3: softmax (8 blocks, one row each) ============
__global__ __launch_bounds__(1024) void softmax_kernel(
    const float* __restrict__ energy, const float* __restrict__ bmin,
    const float* __restrict__ bmax, float* __restrict__ att)
{
    const int b = blockIdx.x, tid = threadIdx.x;
    const int lane = tid & 63, wid = tid >> 6;     // 16 waves
    __shared__ float smn[16], smx[16], sred[16], bc2[2];

    float mn = 3.0e38f, mx = -3.0e38f;
    if (tid < 512) { mn = bmin[tid]; mx = bmax[tid]; }
    #pragma unroll
    for (int s = 32; s > 0; s >>= 1) {
        mn = fminf(mn, __shfl_xor(mn, s));
        mx = fmaxf(mx, __shfl_xor(mx, s));
    }
    if (lane == 0) { smn[wid] = mn; smx[wid] = mx; }
    __syncthreads();
    if (tid == 0) {
        float a = smn[0], m = smx[0];
        #pragma unroll
        for (int i = 1; i < 16; ++i) { a = fminf(a, smn[i]); m = fmaxf(m, smx[i]); }
        bc2[0] = a; bc2[1] = m;
    }
    __syncthreads();
    const float gmn = bc2[0];
    const float inv = 1.0f / (bc2[1] - gmn);

    float4 v = ((const float4*)energy)[b*1024 + tid];
    float4 e;
    e.x = __expf((v.x - gmn) * inv);
    e.y = __expf((v.y - gmn) * inv);
    e.z = __expf((v.z - gmn) * inv);
    e.w = __expf((v.w - gmn) * inv);
    float loc = e.x + e.y + e.z + e.w;
    #pragma unroll
    for (int s = 32; s > 0; s >>= 1) loc += __shfl_down(loc, s);
    if (lane == 0) sred[wid] = loc;
    __syncthreads();
    if (tid == 0) {
        float a = 0.f;
        #pragma unroll
        for (int j = 0; j < 16; ++j) a += sred[j];
        bc2[0] = 1.0f / a;
    }
    __syncthreads();
    const float r = bc2[0];
    e.x *= r; e.y *= r; e.z *= r; e.w *= r;
    ((float4*)att)[b*1024 + tid] = e;
}

// ============ Kernel 4: recombination ============
// grid 8192 = (b = bid&7, hg = (bid>>3)&3, c = bid>>5), block 128 (w).
__global__ __launch_bounds__(128) void out_kernel(
    const float* __restrict__ t2,
    const float* __restrict__ valH, const float* __restrict__ valW,
    const float* __restrict__ att, float* __restrict__ out)
{
    const int bid = blockIdx.x;
    const int b  = bid & 7;
    const int hg = (bid >> 3) & 3;
    const int c  = bid >> 5;
    const int w  = threadIdx.x;
    const size_t pb = ((size_t)b * CC + c) * 2048;
    const float* vH = valH + pb;                        // [k][w]
    const float* vW = valW + pb;                        // [h][k]
    const float* aH = att + (size_t)b * 4096;           // [h][16]
    const float* aW = att + (size_t)b * 4096 + 2048;    // [w][16]
    const size_t tb = ((size_t)b * CC + c) * HW;

    float vHr[16];
    #pragma unroll
    for (int k = 0; k < 16; ++k) vHr[k] = vH[k * WW + w];

    float aWr[16];
    {
        const float4* p = (const float4*)(aW + w * 16);
        float4 q0 = p[0], q1 = p[1], q2 = p[2], q3 = p[3];
        aWr[0]=q0.x; aWr[1]=q0.y; aWr[2]=q0.z; aWr[3]=q0.w;
        aWr[4]=q1.x; aWr[5]=q1.y; aWr[6]=q1.z; aWr[7]=q1.w;
        aWr[8]=q2.x; aWr[9]=q2.y; aWr[10]=q2.z; aWr[11]=q2.w;
        aWr[12]=q3.x; aWr[13]=q3.y; aWr[14]=q3.z; aWr[15]=q3.w;
    }

    const int hbase = hg * 32;
    #pragma unroll 2
    for (int i = 0; i < 32; ++i) {
        const int h = hbase + i;
        const float tv = t2[tb + (size_t)h * WW + w];
        const float* ah = aH + h * 16;      // wave-uniform, contiguous 64B
        const float* vw = vW + h * 16;      // wave-uniform, contiguous 64B
        float accH = 0.f, accW = 0.f;
        #pragma unroll
        for (int k = 0; k < 16; ++k) {
            accH = fmaf(vHr[k], ah[k], accH);
            accW = fmaf(aWr[k], vw[k], accW);
        }
        out[tb + (size_t)h * WW + w] = 0.5f * (accH + accW) + tv;
    }
}

extern "C" void kernel_launch(void* const* d_in, const int* in_sizes, int n_in,
                              void* d_out, int out_size, void* d_ws, size_t ws_size,
                              hipStream_t stream)
{
    const float* t1 = (const float*)d_in[0];
    const float* t2 = (const float*)d_in[1];
    float* out = (float*)d_out;
    float* ws  = (float*)d_ws;

    float* valH   = ws;                               // 4,194,304 floats
    float* valW   = ws + (size_t)4194304;             // 4,194,304
    float* energy = ws + (size_t)8388608;             //    32,768
    float* att    = ws + (size_t)8421376;             //    32,768
    float* bmin   = ws + (size_t)8454144;             //       512
    float* bmax   = ws + (size_t)8454656;             //       512

    // partials live in d_out (33.5 MB of 134 MB), overwritten by out_kernel
    float* PH = out;                                   // 4,194,304 floats
    float* PW = out + (size_t)4194304;                 // 4,194,304 floats

    hipLaunchKernelGGL(fused_pool_energy, dim3(2048), dim3(512), 0, stream,
                       t1, t2, valH, valW, PH, PW);
    hipLaunchKernelGGL(energy_reduce, dim3(512), dim3(256), 0, stream,
                       PH, PW, energy, bmin, bmax);
    hipLaunchKernelGGL(softmax_kernel, dim3(8), dim3(1024), 0, stream,
                       energy, bmin, bmax, att);
    hipLaunchKernelGGL(out_kernel, dim3(8192), dim3(128), 0, stream,
                       t2, valH, valW, att, out);
}